// Round 3
// baseline (1671.826 us; speedup 1.0000x reference)
//
#include <hip/hip_runtime.h>

// ---------------------------------------------------------------------------
// GCN forward, CSR-sorted aggregation (no atomics in hot path):
//   build: deg count -> prefix sum (rowptr) -> counting-sort fill (src_sorted)
//   3x: GEMM (fp32, LDS-tiled) -> agg (wave/node float4 gather, 2 edges/iter)
//   pool head: per-node dot (wave reduce) -> 64 graph accumulators -> out
// All feature matrices [N,128] row-major fp32.
// ---------------------------------------------------------------------------

__global__ __launch_bounds__(256) void count_deg_kernel(const int* __restrict__ col,
                                                        int* __restrict__ deg, int E) {
    int e = blockIdx.x * 256 + threadIdx.x;
    if (e < E) atomicAdd(&deg[col[e]], 1);
}

// per-block exclusive scan of deg (1024 elems/block) -> rowptr; block totals out
__global__ __launch_bounds__(256) void scan1_kernel(const int* __restrict__ deg,
                                                    int* __restrict__ rowptr,
                                                    int* __restrict__ blockSums, int N) {
    __shared__ int ts[256];
    const int t = threadIdx.x;
    const int base = blockIdx.x * 1024 + t * 4;
    int v0 = 0, v1 = 0, v2 = 0, v3 = 0;
    if (base + 3 < N) {
        int4 v = *(const int4*)&deg[base];
        v0 = v.x; v1 = v.y; v2 = v.z; v3 = v.w;
    } else {
        if (base + 0 < N) v0 = deg[base + 0];
        if (base + 1 < N) v1 = deg[base + 1];
        if (base + 2 < N) v2 = deg[base + 2];
        if (base + 3 < N) v3 = deg[base + 3];
    }
    const int tot = v0 + v1 + v2 + v3;
    ts[t] = tot;
    __syncthreads();
    for (int off = 1; off < 256; off <<= 1) {
        int add = (t >= off) ? ts[t - off] : 0;
        __syncthreads();
        ts[t] += add;
        __syncthreads();
    }
    const int excl = ts[t] - tot;
    if (base + 0 < N) rowptr[base + 0] = excl;
    if (base + 1 < N) rowptr[base + 1] = excl + v0;
    if (base + 2 < N) rowptr[base + 2] = excl + v0 + v1;
    if (base + 3 < N) rowptr[base + 3] = excl + v0 + v1 + v2;
    if (t == 255) blockSums[blockIdx.x] = ts[255];
}

__global__ __launch_bounds__(128) void scan2_kernel(const int* __restrict__ blockSums,
                                                    int* __restrict__ blockOffs, int B) {
    __shared__ int ts[128];
    const int t = threadIdx.x;
    ts[t] = (t < B) ? blockSums[t] : 0;
    __syncthreads();
    for (int off = 1; off < 128; off <<= 1) {
        int add = (t >= off) ? ts[t - off] : 0;
        __syncthreads();
        ts[t] += add;
        __syncthreads();
    }
    if (t < B) blockOffs[t] = ts[t];
}

__global__ __launch_bounds__(256) void scan3_kernel(int* __restrict__ rowptr,
                                                    const int* __restrict__ blockOffs, int N) {
    int i = blockIdx.x * 256 + threadIdx.x;
    if (i >= N) return;
    int b = i >> 10;
    if (b > 0) rowptr[i] += blockOffs[b - 1];
}

__global__ __launch_bounds__(256) void dinv_kernel(int* __restrict__ degi,
                                                   float* __restrict__ dinv, int N) {
    int n = blockIdx.x * 256 + threadIdx.x;
    if (n < N) dinv[n] = 1.0f / sqrtf((float)degi[n] + 1.0f);  // +1 = self loop
}

// counting-sort fill; rowptr-shift trick: after fill, bucket c = [rowptr[c-1], rowptr[c])
__global__ __launch_bounds__(256) void fill_kernel(const int* __restrict__ ei,
                                                   int* __restrict__ rowptr,
                                                   int* __restrict__ src_sorted, int E) {
    int e = blockIdx.x * 256 + threadIdx.x;
    if (e >= E) return;
    int c = ei[E + e];
    int pos = atomicAdd(&rowptr[c], 1);
    src_sorted[pos] = ei[e];
}

// T[N,128] = act(H[N,128]) @ W[128,128]; act = relu if applyRelu (deferred relu)
__global__ __launch_bounds__(256) void gemm128_kernel(const float* __restrict__ H,
                                                      const float* __restrict__ W,
                                                      float* __restrict__ T,
                                                      int N, int applyRelu) {
    __shared__ float Ws[64 * 128];
    __shared__ float xs[32 * 132];
    const int tid = threadIdx.x;
    const int row0 = blockIdx.x * 32;

    {
        const float4* H4 = (const float4*)H;
        #pragma unroll
        for (int i = 0; i < 4; ++i) {
            int lin = tid + i * 256;
            int r = lin >> 5;
            int k4 = lin & 31;
            int gr = row0 + r;
            float4 v = make_float4(0.f, 0.f, 0.f, 0.f);
            if (gr < N) v = H4[(size_t)gr * 32 + k4];
            if (applyRelu) {
                v.x = fmaxf(v.x, 0.f); v.y = fmaxf(v.y, 0.f);
                v.z = fmaxf(v.z, 0.f); v.w = fmaxf(v.w, 0.f);
            }
            *(float4*)&xs[r * 132 + k4 * 4] = v;
        }
    }

    const int c = (tid & 31) * 4;
    const int r0 = (tid >> 5) * 4;
    float acc[4][4];
    #pragma unroll
    for (int i = 0; i < 4; ++i)
        #pragma unroll
        for (int j = 0; j < 4; ++j) acc[i][j] = 0.f;

    for (int p = 0; p < 2; ++p) {
        __syncthreads();
        {
            const float4* W4 = (const float4*)(W + p * 64 * 128);
            float4* Ws4 = (float4*)Ws;
            #pragma unroll
            for (int i = 0; i < 8; ++i) Ws4[tid + i * 256] = W4[tid + i * 256];
        }
        __syncthreads();
        const int kbase = p * 64;
        #pragma unroll 4
        for (int k = 0; k < 64; k += 4) {
            float4 xv[4];
            #pragma unroll
            for (int i = 0; i < 4; ++i)
                xv[i] = *(const float4*)&xs[(r0 + i) * 132 + kbase + k];
            #pragma unroll
            for (int kk = 0; kk < 4; ++kk) {
                float4 wv = *(const float4*)&Ws[(k + kk) * 128 + c];
                #pragma unroll
                for (int i = 0; i < 4; ++i) {
                    float xk = (kk == 0) ? xv[i].x : (kk == 1) ? xv[i].y
                             : (kk == 2) ? xv[i].z : xv[i].w;
                    acc[i][0] = fmaf(xk, wv.x, acc[i][0]);
                    acc[i][1] = fmaf(xk, wv.y, acc[i][1]);
                    acc[i][2] = fmaf(xk, wv.z, acc[i][2]);
                    acc[i][3] = fmaf(xk, wv.w, acc[i][3]);
                }
            }
        }
    }
    #pragma unroll
    for (int i = 0; i < 4; ++i) {
        int gr = row0 + r0 + i;
        if (gr < N)
            *(float4*)&T[(size_t)gr * 128 + c] =
                make_float4(acc[i][0], acc[i][1], acc[i][2], acc[i][3]);
    }
}

// one wave per node, float4 lanes (16B sweet spot), 2 edges per iteration:
// lanes 0-31 take even-offset edges, lanes 32-63 odd-offset; halves merged via shfl_xor.
// B[n,:] = dinv[n]^2*A[n,:] + bias + sum_e dinv[n]*dinv[s_e]*A[s_e,:]
__global__ __launch_bounds__(256) void agg_kernel(const int* __restrict__ rowptr,
                                                  const int* __restrict__ src,
                                                  const float* __restrict__ dinv,
                                                  const float* __restrict__ A,
                                                  const float* __restrict__ bias,
                                                  float* __restrict__ B, int N) {
    int w = (blockIdx.x * 256 + threadIdx.x) >> 6;
    if (w >= N) return;
    const int lane = threadIdx.x & 63;
    const int half = lane >> 5;        // 0: even edges, 1: odd edges
    const int q = lane & 31;           // float4 column index
    const int beg = (w > 0) ? rowptr[w - 1] : 0;
    const int end = rowptr[w];
    const float dn = dinv[w];
    const float4* A4 = (const float4*)A;

    float4 acc = make_float4(0.f, 0.f, 0.f, 0.f);
    for (int e = beg + half; e < end; e += 2) {
        int s = src[e];
        float nrm = dn * dinv[s];
        float4 v = A4[(size_t)s * 32 + q];
        acc.x = fmaf(nrm, v.x, acc.x);
        acc.y = fmaf(nrm, v.y, acc.y);
        acc.z = fmaf(nrm, v.z, acc.z);
        acc.w = fmaf(nrm, v.w, acc.w);
    }
    // merge the two halves (lane q <-> lane q+32)
    acc.x += __shfl_xor(acc.x, 32);
    acc.y += __shfl_xor(acc.y, 32);
    acc.z += __shfl_xor(acc.z, 32);
    acc.w += __shfl_xor(acc.w, 32);

    if (half == 0) {
        float4 a = A4[(size_t)w * 32 + q];
        float4 bv = ((const float4*)bias)[q];
        float d2 = dn * dn;
        acc.x = fmaf(d2, a.x, acc.x + bv.x);
        acc.y = fmaf(d2, a.y, acc.y + bv.y);
        acc.z = fmaf(d2, a.z, acc.z + bv.z);
        acc.w = fmaf(d2, a.w, acc.w + bv.w);
        ((float4*)B)[(size_t)w * 32 + q] = acc;
    }
}

// one wave per node: s = dot(relu(H[n,:]), lin_w); atomic into per-graph sums
__global__ __launch_bounds__(256) void nodedot_kernel(const float* __restrict__ H,
                                                      const int* __restrict__ batch,
                                                      const float* __restrict__ lin_w,
                                                      float* __restrict__ gsum,
                                                      float* __restrict__ gcnt, int N) {
    int w = (blockIdx.x * 256 + threadIdx.x) >> 6;
    if (w >= N) return;
    const int lane = threadIdx.x & 63;
    float2 v = ((const float2*)(H + (size_t)w * 128))[lane];
    float2 wv = ((const float2*)lin_w)[lane];
    float s = fmaxf(v.x, 0.f) * wv.x + fmaxf(v.y, 0.f) * wv.y;
    #pragma unroll
    for (int o = 32; o > 0; o >>= 1) s += __shfl_xor(s, o);
    if (lane == 0) {
        int g = batch[w];
        atomicAdd(&gsum[g], s);
        atomicAdd(&gcnt[g], 1.0f);
    }
}

__global__ __launch_bounds__(64) void out_kernel(const float* __restrict__ gsum,
                                                 const float* __restrict__ gcnt,
                                                 const float* __restrict__ lin_b,
                                                 float* __restrict__ out, int G) {
    int g = blockIdx.x * 64 + threadIdx.x;
    if (g < G) out[g] = gsum[g] / fmaxf(gcnt[g], 1.0f) + lin_b[0];
}

extern "C" void kernel_launch(void* const* d_in, const int* in_sizes, int n_in,
                              void* d_out, int out_size, void* d_ws, size_t ws_size,
                              hipStream_t stream) {
    const float* x     = (const float*)d_in[0];
    const int*   ei    = (const int*)d_in[1];    // [2,E]: rows then cols
    const int*   batch = (const int*)d_in[2];
    const float* W1    = (const float*)d_in[3];
    const float* b1    = (const float*)d_in[4];
    const float* W2    = (const float*)d_in[5];
    const float* b2    = (const float*)d_in[6];
    const float* W3    = (const float*)d_in[7];
    const float* b3    = (const float*)d_in[8];
    const float* lin_w = (const float*)d_in[9];
    const float* lin_b = (const float*)d_in[10];
    float* out = (float*)d_out;

    const int N = in_sizes[0] / 128;
    const int E = in_sizes[1] / 2;
    const int G = out_size;
    const int nBlk = (N + 1023) / 1024;

    // workspace: A | B | deg | dinv | rowptr | src_sorted | scan tmp | gsum | gcnt
    float* A         = (float*)d_ws;
    float* B         = A + (size_t)N * 128;
    int*   deg       = (int*)(B + (size_t)N * 128);
    float* dinv      = (float*)(deg + N);
    int*   rowptr    = (int*)(dinv + N);
    int*   src_srt   = rowptr + N;
    int*   blockSums = src_srt + E;
    int*   blockOffs = blockSums + 256;
    float* gsum      = (float*)(blockOffs + 256);
    float* gcnt      = gsum + G;

    // ---- CSR build (once per call, reused by all 3 layers) ----
    hipMemsetAsync(deg, 0, (size_t)N * sizeof(int), stream);
    count_deg_kernel<<<(E + 255) / 256, 256, 0, stream>>>(ei + E, deg, E);
    scan1_kernel<<<nBlk, 256, 0, stream>>>(deg, rowptr, blockSums, N);
    scan2_kernel<<<1, 128, 0, stream>>>(blockSums, blockOffs, nBlk);
    scan3_kernel<<<(N + 255) / 256, 256, 0, stream>>>(rowptr, blockOffs, N);
    dinv_kernel<<<(N + 255) / 256, 256, 0, stream>>>(deg, dinv, N);
    fill_kernel<<<(E + 255) / 256, 256, 0, stream>>>(ei, rowptr, src_srt, E);

    const float* Ws[3] = {W1, W2, W3};
    const float* bs[3] = {b1, b2, b3};
    for (int l = 0; l < 3; ++l) {
        gemm128_kernel<<<(N + 31) / 32, 256, 0, stream>>>(l == 0 ? x : B, Ws[l], A, N,
                                                          l == 0 ? 0 : 1);
        agg_kernel<<<((size_t)N * 64 + 255) / 256, 256, 0, stream>>>(rowptr, src_srt,
                                                                     dinv, A, bs[l], B, N);
    }

    hipMemsetAsync(gsum, 0, 2 * (size_t)G * sizeof(float), stream);
    nodedot_kernel<<<((size_t)N * 64 + 255) / 256, 256, 0, stream>>>(B, batch, lin_w,
                                                                     gsum, gcnt, N);
    out_kernel<<<1, 64, 0, stream>>>(gsum, gcnt, lin_b, out, G);
}

// Round 4
// 864.200 us; speedup vs baseline: 1.9345x; 1.9345x over previous
//
#include <hip/hip_runtime.h>

// ---------------------------------------------------------------------------
// GCN forward, CSR-sorted aggregation (no atomics in hot path):
//   build: deg count -> prefix sum (rowptr) -> counting-sort fill (src_sorted)
//   3x: GEMM (fp32, LDS-tiled) -> agg (wave/node float4 gather, 2 edges/iter)
//   pool head: per-node dot -> nodeval[N] -> per-graph segmented block reduce
// All feature matrices [N,128] row-major fp32.
// ---------------------------------------------------------------------------

__global__ __launch_bounds__(256) void count_deg_kernel(const int* __restrict__ col,
                                                        int* __restrict__ deg, int E) {
    int e = blockIdx.x * 256 + threadIdx.x;
    if (e < E) atomicAdd(&deg[col[e]], 1);
}

// per-block exclusive scan of deg (1024 elems/block) -> rowptr; block totals out
__global__ __launch_bounds__(256) void scan1_kernel(const int* __restrict__ deg,
                                                    int* __restrict__ rowptr,
                                                    int* __restrict__ blockSums, int N) {
    __shared__ int ts[256];
    const int t = threadIdx.x;
    const int base = blockIdx.x * 1024 + t * 4;
    int v0 = 0, v1 = 0, v2 = 0, v3 = 0;
    if (base + 3 < N) {
        int4 v = *(const int4*)&deg[base];
        v0 = v.x; v1 = v.y; v2 = v.z; v3 = v.w;
    } else {
        if (base + 0 < N) v0 = deg[base + 0];
        if (base + 1 < N) v1 = deg[base + 1];
        if (base + 2 < N) v2 = deg[base + 2];
        if (base + 3 < N) v3 = deg[base + 3];
    }
    const int tot = v0 + v1 + v2 + v3;
    ts[t] = tot;
    __syncthreads();
    for (int off = 1; off < 256; off <<= 1) {
        int add = (t >= off) ? ts[t - off] : 0;
        __syncthreads();
        ts[t] += add;
        __syncthreads();
    }
    const int excl = ts[t] - tot;
    if (base + 0 < N) rowptr[base + 0] = excl;
    if (base + 1 < N) rowptr[base + 1] = excl + v0;
    if (base + 2 < N) rowptr[base + 2] = excl + v0 + v1;
    if (base + 3 < N) rowptr[base + 3] = excl + v0 + v1 + v2;
    if (t == 255) blockSums[blockIdx.x] = ts[255];
}

__global__ __launch_bounds__(128) void scan2_kernel(const int* __restrict__ blockSums,
                                                    int* __restrict__ blockOffs, int B) {
    __shared__ int ts[128];
    const int t = threadIdx.x;
    ts[t] = (t < B) ? blockSums[t] : 0;
    __syncthreads();
    for (int off = 1; off < 128; off <<= 1) {
        int add = (t >= off) ? ts[t - off] : 0;
        __syncthreads();
        ts[t] += add;
        __syncthreads();
    }
    if (t < B) blockOffs[t] = ts[t];
}

__global__ __launch_bounds__(256) void scan3_kernel(int* __restrict__ rowptr,
                                                    const int* __restrict__ blockOffs, int N) {
    int i = blockIdx.x * 256 + threadIdx.x;
    if (i >= N) return;
    int b = i >> 10;
    if (b > 0) rowptr[i] += blockOffs[b - 1];
}

__global__ __launch_bounds__(256) void dinv_kernel(int* __restrict__ degi,
                                                   float* __restrict__ dinv, int N) {
    int n = blockIdx.x * 256 + threadIdx.x;
    if (n < N) dinv[n] = 1.0f / sqrtf((float)degi[n] + 1.0f);  // +1 = self loop
}

// counting-sort fill; rowptr-shift trick: after fill, bucket c = [rowptr[c-1], rowptr[c])
__global__ __launch_bounds__(256) void fill_kernel(const int* __restrict__ ei,
                                                   int* __restrict__ rowptr,
                                                   int* __restrict__ src_sorted, int E) {
    int e = blockIdx.x * 256 + threadIdx.x;
    if (e >= E) return;
    int c = ei[E + e];
    int pos = atomicAdd(&rowptr[c], 1);
    src_sorted[pos] = ei[e];
}

// T[N,128] = act(H[N,128]) @ W[128,128]; act = relu if applyRelu (deferred relu)
__global__ __launch_bounds__(256) void gemm128_kernel(const float* __restrict__ H,
                                                      const float* __restrict__ W,
                                                      float* __restrict__ T,
                                                      int N, int applyRelu) {
    __shared__ float Ws[64 * 128];
    __shared__ float xs[32 * 132];
    const int tid = threadIdx.x;
    const int row0 = blockIdx.x * 32;

    {
        const float4* H4 = (const float4*)H;
        #pragma unroll
        for (int i = 0; i < 4; ++i) {
            int lin = tid + i * 256;
            int r = lin >> 5;
            int k4 = lin & 31;
            int gr = row0 + r;
            float4 v = make_float4(0.f, 0.f, 0.f, 0.f);
            if (gr < N) v = H4[(size_t)gr * 32 + k4];
            if (applyRelu) {
                v.x = fmaxf(v.x, 0.f); v.y = fmaxf(v.y, 0.f);
                v.z = fmaxf(v.z, 0.f); v.w = fmaxf(v.w, 0.f);
            }
            *(float4*)&xs[r * 132 + k4 * 4] = v;
        }
    }

    const int c = (tid & 31) * 4;
    const int r0 = (tid >> 5) * 4;
    float acc[4][4];
    #pragma unroll
    for (int i = 0; i < 4; ++i)
        #pragma unroll
        for (int j = 0; j < 4; ++j) acc[i][j] = 0.f;

    for (int p = 0; p < 2; ++p) {
        __syncthreads();
        {
            const float4* W4 = (const float4*)(W + p * 64 * 128);
            float4* Ws4 = (float4*)Ws;
            #pragma unroll
            for (int i = 0; i < 8; ++i) Ws4[tid + i * 256] = W4[tid + i * 256];
        }
        __syncthreads();
        const int kbase = p * 64;
        #pragma unroll 4
        for (int k = 0; k < 64; k += 4) {
            float4 xv[4];
            #pragma unroll
            for (int i = 0; i < 4; ++i)
                xv[i] = *(const float4*)&xs[(r0 + i) * 132 + kbase + k];
            #pragma unroll
            for (int kk = 0; kk < 4; ++kk) {
                float4 wv = *(const float4*)&Ws[(k + kk) * 128 + c];
                #pragma unroll
                for (int i = 0; i < 4; ++i) {
                    float xk = (kk == 0) ? xv[i].x : (kk == 1) ? xv[i].y
                             : (kk == 2) ? xv[i].z : xv[i].w;
                    acc[i][0] = fmaf(xk, wv.x, acc[i][0]);
                    acc[i][1] = fmaf(xk, wv.y, acc[i][1]);
                    acc[i][2] = fmaf(xk, wv.z, acc[i][2]);
                    acc[i][3] = fmaf(xk, wv.w, acc[i][3]);
                }
            }
        }
    }
    #pragma unroll
    for (int i = 0; i < 4; ++i) {
        int gr = row0 + r0 + i;
        if (gr < N)
            *(float4*)&T[(size_t)gr * 128 + c] =
                make_float4(acc[i][0], acc[i][1], acc[i][2], acc[i][3]);
    }
}

// one wave per node, float4 lanes, 2 edges/iter (lanes 0-31 even, 32-63 odd):
// B[n,:] = dinv[n]^2*A[n,:] + bias + sum_e dinv[n]*dinv[s_e]*A[s_e,:]
__global__ __launch_bounds__(256) void agg_kernel(const int* __restrict__ rowptr,
                                                  const int* __restrict__ src,
                                                  const float* __restrict__ dinv,
                                                  const float* __restrict__ A,
                                                  const float* __restrict__ bias,
                                                  float* __restrict__ B, int N) {
    int w = (blockIdx.x * 256 + threadIdx.x) >> 6;
    if (w >= N) return;
    const int lane = threadIdx.x & 63;
    const int half = lane >> 5;
    const int q = lane & 31;
    const int beg = (w > 0) ? rowptr[w - 1] : 0;
    const int end = rowptr[w];
    const float dn = dinv[w];
    const float4* A4 = (const float4*)A;

    float4 acc = make_float4(0.f, 0.f, 0.f, 0.f);
    for (int e = beg + half; e < end; e += 2) {
        int s = src[e];
        float nrm = dn * dinv[s];
        float4 v = A4[(size_t)s * 32 + q];
        acc.x = fmaf(nrm, v.x, acc.x);
        acc.y = fmaf(nrm, v.y, acc.y);
        acc.z = fmaf(nrm, v.z, acc.z);
        acc.w = fmaf(nrm, v.w, acc.w);
    }
    acc.x += __shfl_xor(acc.x, 32);
    acc.y += __shfl_xor(acc.y, 32);
    acc.z += __shfl_xor(acc.z, 32);
    acc.w += __shfl_xor(acc.w, 32);

    if (half == 0) {
        float4 a = A4[(size_t)w * 32 + q];
        float4 bv = ((const float4*)bias)[q];
        float d2 = dn * dn;
        acc.x = fmaf(d2, a.x, acc.x + bv.x);
        acc.y = fmaf(d2, a.y, acc.y + bv.y);
        acc.z = fmaf(d2, a.z, acc.z + bv.z);
        acc.w = fmaf(d2, a.w, acc.w + bv.w);
        ((float4*)B)[(size_t)w * 32 + q] = acc;
    }
}

// one wave per node: nodeval[n] = dot(relu(H[n,:]), lin_w)  (zero atomics)
__global__ __launch_bounds__(256) void nodedot_kernel(const float* __restrict__ H,
                                                      const float* __restrict__ lin_w,
                                                      float* __restrict__ nodeval, int N) {
    int w = (blockIdx.x * 256 + threadIdx.x) >> 6;
    if (w >= N) return;
    const int lane = threadIdx.x & 63;
    float2 v = ((const float2*)(H + (size_t)w * 128))[lane];
    float2 wv = ((const float2*)lin_w)[lane];
    float s = fmaxf(v.x, 0.f) * wv.x + fmaxf(v.y, 0.f) * wv.y;
    #pragma unroll
    for (int o = 32; o > 0; o >>= 1) s += __shfl_xor(s, o);
    if (lane == 0) nodeval[w] = s;
}

__device__ __forceinline__ int lower_bound_dev(const int* __restrict__ a, int n, int key) {
    int lo = 0, hi = n;
    while (lo < hi) {
        int mid = (lo + hi) >> 1;
        if (a[mid] < key) lo = mid + 1; else hi = mid;
    }
    return lo;
}

// one block per graph: out[g] = mean(nodeval[lo:hi]) + lin_b  (batch is sorted)
__global__ __launch_bounds__(256) void segreduce_kernel(const float* __restrict__ nodeval,
                                                        const int* __restrict__ batch,
                                                        const float* __restrict__ lin_b,
                                                        float* __restrict__ out, int N) {
    const int g = blockIdx.x;
    const int lo = lower_bound_dev(batch, N, g);
    const int hi = lower_bound_dev(batch, N, g + 1);
    float acc = 0.f;
    for (int n = lo + threadIdx.x; n < hi; n += 256) acc += nodeval[n];
    __shared__ float red[256];
    red[threadIdx.x] = acc;
    __syncthreads();
    for (int s = 128; s > 0; s >>= 1) {
        if (threadIdx.x < s) red[threadIdx.x] += red[threadIdx.x + s];
        __syncthreads();
    }
    if (threadIdx.x == 0) {
        float cnt = (float)(hi - lo);
        out[g] = red[0] / fmaxf(cnt, 1.0f) + lin_b[0];
    }
}

extern "C" void kernel_launch(void* const* d_in, const int* in_sizes, int n_in,
                              void* d_out, int out_size, void* d_ws, size_t ws_size,
                              hipStream_t stream) {
    const float* x     = (const float*)d_in[0];
    const int*   ei    = (const int*)d_in[1];    // [2,E]: rows then cols
    const int*   batch = (const int*)d_in[2];
    const float* W1    = (const float*)d_in[3];
    const float* b1    = (const float*)d_in[4];
    const float* W2    = (const float*)d_in[5];
    const float* b2    = (const float*)d_in[6];
    const float* W3    = (const float*)d_in[7];
    const float* b3    = (const float*)d_in[8];
    const float* lin_w = (const float*)d_in[9];
    const float* lin_b = (const float*)d_in[10];
    float* out = (float*)d_out;

    const int N = in_sizes[0] / 128;
    const int E = in_sizes[1] / 2;
    const int nBlk = (N + 1023) / 1024;

    // workspace: A | B | deg | dinv | rowptr | src_sorted | scan tmp | nodeval
    float* A         = (float*)d_ws;
    float* B         = A + (size_t)N * 128;
    int*   deg       = (int*)(B + (size_t)N * 128);
    float* dinv      = (float*)(deg + N);
    int*   rowptr    = (int*)(dinv + N);
    int*   src_srt   = rowptr + N;
    int*   blockSums = src_srt + E;
    int*   blockOffs = blockSums + 256;
    float* nodeval   = (float*)(blockOffs + 256);

    // ---- CSR build (once per call, reused by all 3 layers) ----
    hipMemsetAsync(deg, 0, (size_t)N * sizeof(int), stream);
    count_deg_kernel<<<(E + 255) / 256, 256, 0, stream>>>(ei + E, deg, E);
    scan1_kernel<<<nBlk, 256, 0, stream>>>(deg, rowptr, blockSums, N);
    scan2_kernel<<<1, 128, 0, stream>>>(blockSums, blockOffs, nBlk);
    scan3_kernel<<<(N + 255) / 256, 256, 0, stream>>>(rowptr, blockOffs, N);
    dinv_kernel<<<(N + 255) / 256, 256, 0, stream>>>(deg, dinv, N);
    fill_kernel<<<(E + 255) / 256, 256, 0, stream>>>(ei, rowptr, src_srt, E);

    const float* Ws[3] = {W1, W2, W3};
    const float* bs[3] = {b1, b2, b3};
    for (int l = 0; l < 3; ++l) {
        gemm128_kernel<<<(N + 31) / 32, 256, 0, stream>>>(l == 0 ? x : B, Ws[l], A, N,
                                                          l == 0 ? 0 : 1);
        agg_kernel<<<((size_t)N * 64 + 255) / 256, 256, 0, stream>>>(rowptr, src_srt,
                                                                     dinv, A, bs[l], B, N);
    }

    nodedot_kernel<<<((size_t)N * 64 + 255) / 256, 256, 0, stream>>>(B, lin_w, nodeval, N);
    segreduce_kernel<<<64, 256, 0, stream>>>(nodeval, batch, lin_b, out, N);
}